// Round 3
// baseline (81.350 us; speedup 1.0000x reference)
//
#include <hip/hip_runtime.h>

#define SIDE 128
#define PI_F 3.14159265358979f
// Max window half-width: r = sqrt((ln(coef)+32)/c), coef<=2*4pi/0.5=50.27,
// c = pi*4pi/ff_b >= 2*pi^2 = 19.74  =>  r <= 1.35. Use 1.4 for safety.
// Any term beyond |d|>1.4: coef*exp(-c*1.96) < 8e-16; summed < 1e-11. Negligible.
#define RMAX 1.4f
#define BLK 1024

// Single dispatch, one block per batch. Full 128x128 image lives in 64 KB LDS
// (gfx950 allows up to 160 KB/WG): zero it, atom-parallel separable 3x3
// scatter via ds_add (2 atoms/thread, ~60 exps), then coalesced float4 store
// that overwrites the 0xAA poison directly. No hipMemsetAsync node, no global
// atomics, no inter-block ordering. At ~60 us harness floor the only lever
// left is node count + dispatch latency; this is the 1-node version.
__global__ void __launch_bounds__(BLK) potential_onepass(
        const float* __restrict__ coords,
        const float* __restrict__ ff_a,
        const float* __restrict__ ff_b,
        float* __restrict__ out,
        int A) {
    const int b = blockIdx.x;
    const int t = threadIdx.x;

    __shared__ float img[SIDE * SIDE];          // 64 KB

    // ---- zero the LDS image: 4 float4 per thread ----
    float4* iv = (float4*)img;
    #pragma unroll
    for (int k = 0; k < (SIDE * SIDE / 4) / BLK; ++k)
        iv[t + k * BLK] = make_float4(0.f, 0.f, 0.f, 0.f);
    __syncthreads();

    // ---- atom-parallel scatter: 2 rounds at A=2048 ----
    for (int a = t; a < A; a += BLK) {
        const float cx = coords[((size_t)b * A + a) * 3 + 0] + 64.0f;
        const float cy = coords[((size_t)b * A + a) * 3 + 1] + 64.0f;

        if (cx < -RMAX || cx > (float)(SIDE - 1) + RMAX ||
            cy < -RMAX || cy > (float)(SIDE - 1) + RMAX) continue;

        const int j0 = (int)ceilf(cx - RMAX);   // cols j0..j0+2 (superset)
        const int i0 = (int)ceilf(cy - RMAX);   // rows i0..i0+2
        const float dx0 = (float)j0 - cx;
        const float dy0 = (float)i0 - cy;

        float acc[3][3] = {{0.f,0.f,0.f},{0.f,0.f,0.f},{0.f,0.f,0.f}};
        #pragma unroll
        for (int f = 0; f < 5; ++f) {
            const float fb   = ff_b[a * 5 + f];          // coalesced 20 B/lane
            const float invb = (4.0f * PI_F) / fb;
            const float coef = ff_a[a * 5 + f] * invb;   // peak amplitude
            const float c    = PI_F * invb;              // exponent scale
            float wx[3], wy[3];
            #pragma unroll
            for (int k = 0; k < 3; ++k) {
                const float dx = dx0 + (float)k;
                const float dy = dy0 + (float)k;
                wx[k] = __expf(-c * dx * dx);
                wy[k] = coef * __expf(-c * dy * dy);
            }
            #pragma unroll
            for (int ii = 0; ii < 3; ++ii)
                #pragma unroll
                for (int jj = 0; jj < 3; ++jj)
                    acc[ii][jj] += wy[ii] * wx[jj];
        }

        #pragma unroll
        for (int ii = 0; ii < 3; ++ii) {
            const int i = i0 + ii;
            if (i < 0 || i >= SIDE) continue;
            #pragma unroll
            for (int jj = 0; jj < 3; ++jj) {
                const int j = j0 + jj;
                if (j < 0 || j >= SIDE) continue;
                atomicAdd(&img[i * SIDE + j], acc[ii][jj]);   // ds_add
            }
        }
    }
    __syncthreads();

    // ---- coalesced store, overwrites poison: 4 float4 per thread ----
    const float4* src = (const float4*)img;
    float4* dst = (float4*)(out + (size_t)b * SIDE * SIDE);
    #pragma unroll
    for (int k = 0; k < (SIDE * SIDE / 4) / BLK; ++k)
        dst[t + k * BLK] = src[t + k * BLK];
}

extern "C" void kernel_launch(void* const* d_in, const int* in_sizes, int n_in,
                              void* d_out, int out_size, void* d_ws, size_t ws_size,
                              hipStream_t stream) {
    const float* coords = (const float*)d_in[0];
    const float* ffa    = (const float*)d_in[1];
    const float* ffb    = (const float*)d_in[2];
    float* out = (float*)d_out;

    int A = in_sizes[1] / 5;            // 2048 (in_sizes are element counts)
    int B = in_sizes[0] / (A * 3);      // 4

    potential_onepass<<<dim3(B), BLK, 0, stream>>>(coords, ffa, ffb, out, A);
}

// Round 4
// 63.166 us; speedup vs baseline: 1.2879x; 1.2879x over previous
//
#include <hip/hip_runtime.h>

#define SIDE 128
#define PI_F 3.14159265358979f
// Max window half-width: r = sqrt((ln(coef)+32)/c), coef<=2*4pi/0.5=50.27,
// c = pi*4pi/ff_b >= 2*pi^2 = 19.74  =>  r <= 1.35. Use 1.4 for safety.
// Any term beyond |d|>1.4: coef*exp(-c*1.96) < 8e-16; summed < 1e-11. Negligible.
#define RMAX 1.4f
#define BLK 64

// REVERT to the round-2 design (best measured: 62.9 us). Session ladder:
//   R0 stripe+compaction 1-node: 63.8 | R1 divergent 1-node: 68.4
//   R2 memset + atom-scatter:    62.9 | R3 4-block fat 1-node: 81.4
// R3 showed block parallelism is load-bearing (4 WGs -> ~21 us of exposed
// L2-cold latency); R2's 128 single-wave blocks hide it. Harness floor
// (256 MiB ws re-poison fill at 85% HBM + out poison + restores + node
// gaps) ~= 60 us; this design's device work is ~1-2 us on top.
//
// Atom-parallel scatter: one thread per (batch, atom). All input reads are
// once-only and coalesced (ff: contiguous 20 B/lane; coords: 12 B stride).
// Fixed 3x3 window (ceil(c-1.4)..+2 is always a superset of the true
// <=3-wide window; extra pixels contribute < 4e-18). Separable wx (x) wy
// accumulated in registers over the 5 factors, then <=9 predicated global
// atomicAdds (hottest pixel ~26 adds/batch -> negligible serialization).
// out is pre-zeroed by a memset node (graph-capture-safe).
__global__ void __launch_bounds__(BLK) potential_scatter(
        const float* __restrict__ coords,
        const float* __restrict__ ff_a,
        const float* __restrict__ ff_b,
        float* __restrict__ out,
        int A) {
    const int a = blockIdx.x * BLK + threadIdx.x;
    const int b = blockIdx.y;
    if (a >= A) return;

    const float cx = coords[((size_t)b * A + a) * 3 + 0] + 64.0f;
    const float cy = coords[((size_t)b * A + a) * 3 + 1] + 64.0f;

    // whole window off-grid -> nothing to do
    if (cx < -RMAX || cx > (float)(SIDE - 1) + RMAX ||
        cy < -RMAX || cy > (float)(SIDE - 1) + RMAX) return;

    const int j0 = (int)ceilf(cx - RMAX);   // cols j0..j0+2 (superset window)
    const int i0 = (int)ceilf(cy - RMAX);   // rows i0..i0+2
    const float dx0 = (float)j0 - cx;
    const float dy0 = (float)i0 - cy;

    float acc[3][3] = {{0.f, 0.f, 0.f}, {0.f, 0.f, 0.f}, {0.f, 0.f, 0.f}};
    #pragma unroll
    for (int f = 0; f < 5; ++f) {
        const float fb   = ff_b[a * 5 + f];          // coalesced 20 B/lane
        const float invb = (4.0f * PI_F) / fb;
        const float coef = ff_a[a * 5 + f] * invb;   // peak amplitude
        const float c    = PI_F * invb;              // exponent scale
        float wx[3], wy[3];
        #pragma unroll
        for (int k = 0; k < 3; ++k) {
            const float dx = dx0 + (float)k;
            const float dy = dy0 + (float)k;
            wx[k] = __expf(-c * dx * dx);
            wy[k] = coef * __expf(-c * dy * dy);
        }
        #pragma unroll
        for (int ii = 0; ii < 3; ++ii)
            #pragma unroll
            for (int jj = 0; jj < 3; ++jj)
                acc[ii][jj] += wy[ii] * wx[jj];
    }

    float* ob = out + (size_t)b * SIDE * SIDE;
    #pragma unroll
    for (int ii = 0; ii < 3; ++ii) {
        const int i = i0 + ii;
        if (i < 0 || i >= SIDE) continue;
        #pragma unroll
        for (int jj = 0; jj < 3; ++jj) {
            const int j = j0 + jj;
            if (j < 0 || j >= SIDE) continue;
            atomicAdd(&ob[i * SIDE + j], acc[ii][jj]);
        }
    }
}

extern "C" void kernel_launch(void* const* d_in, const int* in_sizes, int n_in,
                              void* d_out, int out_size, void* d_ws, size_t ws_size,
                              hipStream_t stream) {
    const float* coords = (const float*)d_in[0];
    const float* ffa    = (const float*)d_in[1];
    const float* ffb    = (const float*)d_in[2];
    float* out = (float*)d_out;

    int A = in_sizes[1] / 5;            // 2048 (in_sizes are element counts)
    int B = in_sizes[0] / (A * 3);      // 4

    // Zero the (poisoned) output: atomic accumulation base. Graph-capture-safe.
    hipMemsetAsync(out, 0, (size_t)B * SIDE * SIDE * sizeof(float), stream);

    dim3 grid((A + BLK - 1) / BLK, B);  // (32, 4) = 128 single-wave blocks
    potential_scatter<<<grid, BLK, 0, stream>>>(coords, ffa, ffb, out, A);
}